// Round 7
// baseline (152.820 us; speedup 1.0000x reference)
//
#include <hip/hip_runtime.h>

#define NB 2048
#define NN 64
#define NC 256
#define EPSV 1e-5f

typedef __attribute__((ext_vector_type(8))) short bf16x8;
typedef __attribute__((ext_vector_type(4))) float f32x4;

union U8 { unsigned u[4]; unsigned long long d[2]; bf16x8 v; };

__device__ __forceinline__ unsigned f_bits(float f) {
    union { float f; unsigned u; } x; x.f = f; return x.u;
}
// round-half-up f32->bf16
__device__ __forceinline__ unsigned short f2bf_r(float f) {
    return (unsigned short)((f_bits(f) + 0x8000u) >> 16);
}
// pack two f32 -> two bf16 in one u32 (lo = a, hi = b)
__device__ __forceinline__ unsigned pack2(float a, float b) {
    return ((f_bits(a) + 0x8000u) >> 16) | ((f_bits(b) + 0x8000u) & 0xffff0000u);
}

// ---- prep: pack W (f32 [67][256]) into bf16 MFMA B-fragments ----
// frag f = nt*8+kg (nt 0..4, kg 0..7), lane l: 8 bf16 of row o=nt*16+(l&15),
// k = kg*32 + (l>>4)*8 + e.  o >= 67 -> zeros.
extern "C" __global__ void prep_wfrag(const float* __restrict__ W,
                                      unsigned short* __restrict__ wf)
{
    const int idx = blockIdx.x * 256 + threadIdx.x;  // 0..2559
    if (idx >= 40 * 64) return;
    const int f = idx >> 6, l = idx & 63;
    const int nt = f >> 3, kg = f & 7;
    const int o = nt * 16 + (l & 15);
    const int kb = kg * 32 + (l >> 4) * 8;
    float x[8];
#pragma unroll
    for (int e = 0; e < 8; ++e)
        x[e] = (o < 67) ? W[o * NC + kb + e] : 0.f;
    uint4 pk;
    pk.x = pack2(x[0], x[1]); pk.y = pack2(x[2], x[3]);
    pk.z = pack2(x[4], x[5]); pk.w = pack2(x[6], x[7]);
    *(uint4*)(wf + (size_t)idx * 8) = pk;
}

extern "C" __global__ __launch_bounds__(512, 6)
void dysep_mfma8(const float* __restrict__ q, const float* __restrict__ v,
                 const unsigned short* __restrict__ wfrag,
                 const float* __restrict__ bl,
                 const float* __restrict__ gam, const float* __restrict__ bet,
                 float* __restrict__ out)
{
    // LDS: 33792 + 8704 + 1024 + 1024 = 44544 B -> 3 blocks/CU (24 waves)
    __shared__ __align__(16) unsigned short sDT[256 * 66];  // depth^T bf16 [c][n], pitch 66
    __shared__ __align__(16) unsigned short sPw[64][68];    // point_w bf16 [m][n], pitch 68
    __shared__ __align__(16) float sCw[64][4];              // conv weights f32
    __shared__ __align__(16) float sLN[64][4];              // per-row {s1_h0,s2_h0,s1_h1,s2_h1}

    const int tid = threadIdx.x;
    const int w  = tid >> 6;        // wave 0..7
    const int mt = w & 3;           // m-tile 0..3
    const int h  = w >> 2;          // half 0/1
    const int l  = tid & 63;
    const int lr = l & 15;
    const int lg = l >> 4;
    const long base = (long)blockIdx.x * (NN * NC);

    // ---- V prefetch: issue ALL V loads at kernel entry so the HBM round-trip
    // overlaps phase 1. NOTE: every consumer loop below is FULLY unrolled so
    // vpre[] indices are compile-time static (rule #20: runtime-indexed
    // ext-vector arrays spill to scratch -> doubled FETCH/WRITE in round 5). ----
    float4 vpre[8];
#pragma unroll
    for (int i = 0; i < 8; ++i)
        vpre[i] = *(const float4*)(v + base + (long)(i * 8 + w) * NC + 4 * l);

    // ================= Phase 1: dyw = Q @ W^T + b  via MFMA =================
    // wave (mt,h): rows mt*16..+15, nt = h*3 + t, t < (3-h)
    bf16x8 af[8];
    {
        const float* qrow = q + base + (long)(mt * 16 + lr) * NC + lg * 8;
#pragma unroll
        for (int kg = 0; kg < 8; ++kg) {
            float4 a0 = *(const float4*)(qrow + kg * 32);
            float4 a1 = *(const float4*)(qrow + kg * 32 + 4);
            U8 u;
            u.u[0] = pack2(a0.x, a0.y); u.u[1] = pack2(a0.z, a0.w);
            u.u[2] = pack2(a1.x, a1.y); u.u[3] = pack2(a1.z, a1.w);
            af[kg] = u.v;
        }
    }
    const int ntCount = 3 - h;
    f32x4 acc[3];
    {
        f32x4 zz = {0.f, 0.f, 0.f, 0.f};
#pragma unroll
        for (int t = 0; t < 3; ++t) acc[t] = zz;
    }
    const U8* __restrict__ wf8 = (const U8*)wfrag;
#pragma unroll
    for (int t = 0; t < 3; ++t) {
        if (t < ntCount) {
            const int nt = h * 3 + t;
            const U8* fr = wf8 + (nt * 8) * 64 + l;
#pragma unroll
            for (int kg = 0; kg < 8; ++kg) {
                U8 u = fr[kg * 64];
                acc[t] = __builtin_amdgcn_mfma_f32_16x16x32_bf16(af[kg], u.v, acc[t], 0, 0, 0);
            }
        }
    }
    // epilogue: C/D layout col=lr (o within tile), row=lg*4+r (m within tile)
#pragma unroll
    for (int t = 0; t < 3; ++t) {
        if (t < ntCount) {
            const int o = (h * 3 + t) * 16 + lr;
            const float bb = (o < 67) ? bl[o] : 0.f;
#pragma unroll
            for (int r = 0; r < 4; ++r) {
                const int m = mt * 16 + lg * 4 + r;
                const float val = acc[t][r] + bb;
                if (o < 3) sCw[m][o] = val;
                else if (o < 67) sPw[m][o - 3] = f2bf_r(val);
            }
        }
    }
    __syncthreads();

    // ====== Phase 2: depth^T[c][n] = relu(conv3(V[n], cw[n])) (bf16) ======
    {
#pragma unroll
        for (int i = 0; i < 8; ++i) {       // FULL unroll: vpre[i] must be static
            const int n = i * 8 + w;
            const float w0 = sCw[n][0], w1 = sCw[n][1], w2 = sCw[n][2];
            float4 vv = vpre[i];
            float prev = __shfl(vv.w, (l + 63) & 63);
            float next = __shfl(vv.x, (l + 1) & 63);
            if (l == 0) prev = 0.f;
            if (l == 63) next = 0.f;
            const float d0 = fmaxf(0.f, w0 * prev + w1 * vv.x + w2 * vv.y);
            const float d1 = fmaxf(0.f, w0 * vv.x + w1 * vv.y + w2 * vv.z);
            const float d2 = fmaxf(0.f, w0 * vv.y + w1 * vv.z + w2 * vv.w);
            const float d3 = fmaxf(0.f, w0 * vv.z + w1 * vv.w + w2 * next);
            const int c0 = 4 * l;
            sDT[(c0 + 0) * 66 + n] = f2bf_r(d0);
            sDT[(c0 + 1) * 66 + n] = f2bf_r(d1);
            sDT[(c0 + 2) * 66 + n] = f2bf_r(d2);
            sDT[(c0 + 3) * 66 + n] = f2bf_r(d3);
        }
    }
    __syncthreads();

    // ======== Phase 3: point = pw @ depth via MFMA (wave: mt x c-half h) ========
    bf16x8 pa[2];
#pragma unroll
    for (int kg = 0; kg < 2; ++kg) {
        const unsigned long long* p =
            (const unsigned long long*)&sPw[mt * 16 + lr][kg * 32 + lg * 8];
        U8 u; u.d[0] = p[0]; u.d[1] = p[1];
        pa[kg] = u.v;
    }
    f32x4 acc3[8];
    {
        f32x4 zz = {0.f, 0.f, 0.f, 0.f};
#pragma unroll
        for (int t = 0; t < 8; ++t) acc3[t] = zz;
    }
#pragma unroll
    for (int t = 0; t < 8; ++t) {
        const int ct = h * 8 + t;
#pragma unroll
        for (int kg = 0; kg < 2; ++kg) {
            const unsigned* p = (const unsigned*)&sDT[(ct * 16 + lr) * 66 + kg * 32 + lg * 8];
            U8 u; u.u[0] = p[0]; u.u[1] = p[1]; u.u[2] = p[2]; u.u[3] = p[3];
            acc3[t] = __builtin_amdgcn_mfma_f32_16x16x32_bf16(pa[kg], u.v, acc3[t], 0, 0, 0);
        }
    }
    // partial LN sums over this wave's 8 c-tiles; butterfly over lr (within 16)
    {
        float s1a[4], s2a[4];
#pragma unroll
        for (int r = 0; r < 4; ++r) {
            float s1 = 0.f, s2 = 0.f;
#pragma unroll
            for (int t = 0; t < 8; ++t) {
                const float x = acc3[t][r];
                s1 += x; s2 += x * x;
            }
#pragma unroll
            for (int off = 1; off < 16; off <<= 1) {
                s1 += __shfl_xor(s1, off);
                s2 += __shfl_xor(s2, off);
            }
            s1a[r] = s1; s2a[r] = s2;
        }
        if (lr == 0) {
#pragma unroll
            for (int r = 0; r < 4; ++r) {
                const int m = mt * 16 + lg * 4 + r;
                sLN[m][2 * h + 0] = s1a[r];
                sLN[m][2 * h + 1] = s2a[r];
            }
        }
    }
    __syncthreads();

    float mus[4], rss[4];
#pragma unroll
    for (int r = 0; r < 4; ++r) {
        const int m = mt * 16 + lg * 4 + r;
        const float S1 = sLN[m][0] + sLN[m][2];
        const float S2 = sLN[m][1] + sLN[m][3];
        const float mu = S1 * (1.f / 256.f);
        const float var = S2 * (1.f / 256.f) - mu * mu;
        mus[r] = mu;
        rss[r] = rsqrtf(var + EPSV);
    }
    {
        float* orow = out + base + (long)(mt * 16 + lg * 4) * NC + lr;
#pragma unroll
        for (int t = 0; t < 8; ++t) {
            const int ct = h * 8 + t;
            const float gg = gam[ct * 16 + lr];
            const float bb = bet[ct * 16 + lr];
#pragma unroll
            for (int r = 0; r < 4; ++r) {
                orow[(long)r * NC + ct * 16] =
                    (acc3[t][r] - mus[r]) * rss[r] * gg + bb;
            }
        }
    }
}

extern "C" void kernel_launch(void* const* d_in, const int* in_sizes, int n_in,
                              void* d_out, int out_size, void* d_ws, size_t ws_size,
                              hipStream_t stream) {
    const float* q   = (const float*)d_in[0];
    const float* v   = (const float*)d_in[1];
    const float* W   = (const float*)d_in[2];
    const float* bl  = (const float*)d_in[3];
    const float* gam = (const float*)d_in[4];
    const float* bet = (const float*)d_in[5];
    float* o = (float*)d_out;
    unsigned short* wf = (unsigned short*)d_ws;   // 40*64*16 B = 40960 B

    hipLaunchKernelGGL(prep_wfrag, dim3(10), dim3(256), 0, stream, W, wf);
    hipLaunchKernelGGL(dysep_mfma8, dim3(NB), dim3(512), 0, stream,
                       q, v, wf, bl, gam, bet, o);
}

// Round 8
// 119.613 us; speedup vs baseline: 1.2776x; 1.2776x over previous
//
#include <hip/hip_runtime.h>

#define NB 2048
#define NN 64
#define NC 256
#define EPSV 1e-5f

typedef __attribute__((ext_vector_type(8))) short bf16x8;
typedef __attribute__((ext_vector_type(4))) float f32x4;

union U8 { unsigned u[4]; unsigned long long d[2]; bf16x8 v; };

__device__ __forceinline__ unsigned f_bits(float f) {
    union { float f; unsigned u; } x; x.f = f; return x.u;
}
// round-half-up f32->bf16
__device__ __forceinline__ unsigned short f2bf_r(float f) {
    return (unsigned short)((f_bits(f) + 0x8000u) >> 16);
}
// pack two f32 -> two bf16 in one u32 (lo = a, hi = b)
__device__ __forceinline__ unsigned pack2(float a, float b) {
    return ((f_bits(a) + 0x8000u) >> 16) | ((f_bits(b) + 0x8000u) & 0xffff0000u);
}

// ---- prep: pack W (f32 [67][256]) into bf16 MFMA B-fragments ----
extern "C" __global__ void prep_wfrag(const float* __restrict__ W,
                                      unsigned short* __restrict__ wf)
{
    const int idx = blockIdx.x * 256 + threadIdx.x;  // 0..2559
    if (idx >= 40 * 64) return;
    const int f = idx >> 6, l = idx & 63;
    const int nt = f >> 3, kg = f & 7;
    const int o = nt * 16 + (l & 15);
    const int kb = kg * 32 + (l >> 4) * 8;
    float x[8];
#pragma unroll
    for (int e = 0; e < 8; ++e)
        x[e] = (o < 67) ? W[o * NC + kb + e] : 0.f;
    uint4 pk;
    pk.x = pack2(x[0], x[1]); pk.y = pack2(x[2], x[3]);
    pk.z = pack2(x[4], x[5]); pk.w = pack2(x[6], x[7]);
    *(uint4*)(wf + (size_t)idx * 8) = pk;
}

// ================= K1: dyw = Q @ W^T + b for all batches ==================
// No LDS, no barriers: waves fully independent -> latency self-hiding.
// Writes conv weights (f32 [b][64][4]) and point weights (bf16 [b][64][64]).
extern "C" __global__ __launch_bounds__(512)
void dysep_k1(const float* __restrict__ q, const unsigned short* __restrict__ wfrag,
              const float* __restrict__ bl,
              float* __restrict__ cw_out, unsigned short* __restrict__ pw_out)
{
    const int tid = threadIdx.x;
    const int w  = tid >> 6;        // wave 0..7
    const int mt = w & 3;           // m-tile 0..3
    const int h  = w >> 2;          // half 0/1 (nt split 3/2)
    const int l  = tid & 63;
    const int lr = l & 15;
    const int lg = l >> 4;
    const int b  = blockIdx.x;
    const long base = (long)b * (NN * NC);

    bf16x8 af[8];
    {
        const float* qrow = q + base + (long)(mt * 16 + lr) * NC + lg * 8;
#pragma unroll
        for (int kg = 0; kg < 8; ++kg) {
            float4 a0 = *(const float4*)(qrow + kg * 32);
            float4 a1 = *(const float4*)(qrow + kg * 32 + 4);
            U8 u;
            u.u[0] = pack2(a0.x, a0.y); u.u[1] = pack2(a0.z, a0.w);
            u.u[2] = pack2(a1.x, a1.y); u.u[3] = pack2(a1.z, a1.w);
            af[kg] = u.v;
        }
    }
    const int ntCount = 3 - h;
    f32x4 acc[3];
    {
        f32x4 zz = {0.f, 0.f, 0.f, 0.f};
#pragma unroll
        for (int t = 0; t < 3; ++t) acc[t] = zz;
    }
    const U8* __restrict__ wf8 = (const U8*)wfrag;
#pragma unroll
    for (int t = 0; t < 3; ++t) {
        if (t < ntCount) {
            const int nt = h * 3 + t;
            const U8* fr = wf8 + (nt * 8) * 64 + l;
#pragma unroll
            for (int kg = 0; kg < 8; ++kg) {
                U8 u = fr[kg * 64];
                acc[t] = __builtin_amdgcn_mfma_f32_16x16x32_bf16(af[kg], u.v, acc[t], 0, 0, 0);
            }
        }
    }
    // C/D layout: col=lr (o), row=lg*4+r (m)
#pragma unroll
    for (int t = 0; t < 3; ++t) {
        if (t < ntCount) {
            const int o = (h * 3 + t) * 16 + lr;
            const float bb = (o < 67) ? bl[o] : 0.f;
#pragma unroll
            for (int r = 0; r < 4; ++r) {
                const int m = mt * 16 + lg * 4 + r;
                const float val = acc[t][r] + bb;
                if (o < 3) cw_out[b * 256 + m * 4 + o] = val;
                else if (o < 67) pw_out[(size_t)b * 4096 + m * 64 + (o - 3)] = f2bf_r(val);
            }
        }
    }
}

// ========== K2: conv -> point (MFMA) -> LayerNorm, per batch ==========
extern "C" __global__ __launch_bounds__(512, 6)
void dysep_k2(const float* __restrict__ v, const float* __restrict__ cw_in,
              const unsigned short* __restrict__ pw_in,
              const float* __restrict__ gam, const float* __restrict__ bet,
              float* __restrict__ out)
{
    // LDS: 33792 + 1024 = 34816 B -> up to 4 blocks/CU
    __shared__ __align__(16) unsigned short sDT[256 * 66];  // depth^T bf16 [c][n], pitch 66
    __shared__ __align__(16) float sLN[64][4];

    const int tid = threadIdx.x;
    const int w  = tid >> 6;
    const int mt = w & 3;
    const int h  = w >> 2;
    const int l  = tid & 63;
    const int lr = l & 15;
    const int lg = l >> 4;
    const int b  = blockIdx.x;
    const long base = (long)b * (NN * NC);

    // ---- conv: loads are the FIRST instructions; no cross-barrier live ranges ----
#pragma unroll
    for (int i = 0; i < 8; ++i) {
        const int n = i * 8 + w;
        float4 vv  = *(const float4*)(v + base + (long)n * NC + 4 * l);
        float4 cwv = *(const float4*)(cw_in + b * 256 + n * 4);  // broadcast
        float prev = __shfl(vv.w, (l + 63) & 63);
        float next = __shfl(vv.x, (l + 1) & 63);
        if (l == 0) prev = 0.f;
        if (l == 63) next = 0.f;
        const float d0 = fmaxf(0.f, cwv.x * prev + cwv.y * vv.x + cwv.z * vv.y);
        const float d1 = fmaxf(0.f, cwv.x * vv.x + cwv.y * vv.y + cwv.z * vv.z);
        const float d2 = fmaxf(0.f, cwv.x * vv.y + cwv.y * vv.z + cwv.z * vv.w);
        const float d3 = fmaxf(0.f, cwv.x * vv.z + cwv.y * vv.w + cwv.z * next);
        const int c0 = 4 * l;
        sDT[(c0 + 0) * 66 + n] = f2bf_r(d0);
        sDT[(c0 + 1) * 66 + n] = f2bf_r(d1);
        sDT[(c0 + 2) * 66 + n] = f2bf_r(d2);
        sDT[(c0 + 3) * 66 + n] = f2bf_r(d3);
    }
    __syncthreads();

    // ---- point = pw @ depth via MFMA (wave: mt x c-half h) ----
    bf16x8 pa[2];
#pragma unroll
    for (int kg = 0; kg < 2; ++kg) {
        const unsigned long long* p = (const unsigned long long*)
            (pw_in + (size_t)b * 4096 + (mt * 16 + lr) * 64 + kg * 32 + lg * 8);
        U8 u; u.d[0] = p[0]; u.d[1] = p[1];
        pa[kg] = u.v;
    }
    f32x4 acc3[8];
    {
        f32x4 zz = {0.f, 0.f, 0.f, 0.f};
#pragma unroll
        for (int t = 0; t < 8; ++t) acc3[t] = zz;
    }
#pragma unroll
    for (int t = 0; t < 8; ++t) {
        const int ct = h * 8 + t;
#pragma unroll
        for (int kg = 0; kg < 2; ++kg) {
            const unsigned* p = (const unsigned*)&sDT[(ct * 16 + lr) * 66 + kg * 32 + lg * 8];
            U8 u; u.u[0] = p[0]; u.u[1] = p[1]; u.u[2] = p[2]; u.u[3] = p[3];
            acc3[t] = __builtin_amdgcn_mfma_f32_16x16x32_bf16(pa[kg], u.v, acc3[t], 0, 0, 0);
        }
    }
    // partial LN sums over this wave's 8 c-tiles; butterfly over lr (within 16)
    {
        float s1a[4], s2a[4];
#pragma unroll
        for (int r = 0; r < 4; ++r) {
            float s1 = 0.f, s2 = 0.f;
#pragma unroll
            for (int t = 0; t < 8; ++t) {
                const float x = acc3[t][r];
                s1 += x; s2 += x * x;
            }
#pragma unroll
            for (int off = 1; off < 16; off <<= 1) {
                s1 += __shfl_xor(s1, off);
                s2 += __shfl_xor(s2, off);
            }
            s1a[r] = s1; s2a[r] = s2;
        }
        if (lr == 0) {
#pragma unroll
            for (int r = 0; r < 4; ++r) {
                const int m = mt * 16 + lg * 4 + r;
                sLN[m][2 * h + 0] = s1a[r];
                sLN[m][2 * h + 1] = s2a[r];
            }
        }
    }
    __syncthreads();

    float mus[4], rss[4];
#pragma unroll
    for (int r = 0; r < 4; ++r) {
        const int m = mt * 16 + lg * 4 + r;
        const float S1 = sLN[m][0] + sLN[m][2];
        const float S2 = sLN[m][1] + sLN[m][3];
        const float mu = S1 * (1.f / 256.f);
        const float var = S2 * (1.f / 256.f) - mu * mu;
        mus[r] = mu;
        rss[r] = rsqrtf(var + EPSV);
    }
    {
        float* orow = out + base + (long)(mt * 16 + lg * 4) * NC + lr;
#pragma unroll
        for (int t = 0; t < 8; ++t) {
            const int ct = h * 8 + t;
            const float gg = gam[ct * 16 + lr];
            const float bb = bet[ct * 16 + lr];
#pragma unroll
            for (int r = 0; r < 4; ++r) {
                orow[(long)r * NC + ct * 16] =
                    (acc3[t][r] - mus[r]) * rss[r] * gg + bb;
            }
        }
    }
}

// ---- fallback: proven round-4 fused kernel (used only if ws too small) ----
extern "C" __global__ __launch_bounds__(512, 6)
void dysep_mfma8(const float* __restrict__ q, const float* __restrict__ v,
                 const unsigned short* __restrict__ wfrag,
                 const float* __restrict__ bl,
                 const float* __restrict__ gam, const float* __restrict__ bet,
                 float* __restrict__ out)
{
    __shared__ __align__(16) unsigned short sDT[256 * 66];
    __shared__ __align__(16) unsigned short sPw[64][68];
    __shared__ __align__(16) float sCw[64][4];
    __shared__ __align__(16) float sLN[64][4];

    const int tid = threadIdx.x;
    const int w  = tid >> 6;
    const int mt = w & 3;
    const int h  = w >> 2;
    const int l  = tid & 63;
    const int lr = l & 15;
    const int lg = l >> 4;
    const long base = (long)blockIdx.x * (NN * NC);

    bf16x8 af[8];
    {
        const float* qrow = q + base + (long)(mt * 16 + lr) * NC + lg * 8;
#pragma unroll
        for (int kg = 0; kg < 8; ++kg) {
            float4 a0 = *(const float4*)(qrow + kg * 32);
            float4 a1 = *(const float4*)(qrow + kg * 32 + 4);
            U8 u;
            u.u[0] = pack2(a0.x, a0.y); u.u[1] = pack2(a0.z, a0.w);
            u.u[2] = pack2(a1.x, a1.y); u.u[3] = pack2(a1.z, a1.w);
            af[kg] = u.v;
        }
    }
    const int ntCount = 3 - h;
    f32x4 acc[3];
    {
        f32x4 zz = {0.f, 0.f, 0.f, 0.f};
#pragma unroll
        for (int t = 0; t < 3; ++t) acc[t] = zz;
    }
    const U8* __restrict__ wf8 = (const U8*)wfrag;
#pragma unroll
    for (int t = 0; t < 3; ++t) {
        if (t < ntCount) {
            const int nt = h * 3 + t;
            const U8* fr = wf8 + (nt * 8) * 64 + l;
#pragma unroll
            for (int kg = 0; kg < 8; ++kg) {
                U8 u = fr[kg * 64];
                acc[t] = __builtin_amdgcn_mfma_f32_16x16x32_bf16(af[kg], u.v, acc[t], 0, 0, 0);
            }
        }
    }
#pragma unroll
    for (int t = 0; t < 3; ++t) {
        if (t < ntCount) {
            const int o = (h * 3 + t) * 16 + lr;
            const float bb = (o < 67) ? bl[o] : 0.f;
#pragma unroll
            for (int r = 0; r < 4; ++r) {
                const int m = mt * 16 + lg * 4 + r;
                const float val = acc[t][r] + bb;
                if (o < 3) sCw[m][o] = val;
                else if (o < 67) sPw[m][o - 3] = f2bf_r(val);
            }
        }
    }
    __syncthreads();

    {
#pragma unroll 4
        for (int i = 0; i < 8; ++i) {
            const int n = i * 8 + w;
            const float w0 = sCw[n][0], w1 = sCw[n][1], w2 = sCw[n][2];
            float4 vv = *(const float4*)(v + base + (long)n * NC + 4 * l);
            float prev = __shfl(vv.w, (l + 63) & 63);
            float next = __shfl(vv.x, (l + 1) & 63);
            if (l == 0) prev = 0.f;
            if (l == 63) next = 0.f;
            const float d0 = fmaxf(0.f, w0 * prev + w1 * vv.x + w2 * vv.y);
            const float d1 = fmaxf(0.f, w0 * vv.x + w1 * vv.y + w2 * vv.z);
            const float d2 = fmaxf(0.f, w0 * vv.y + w1 * vv.z + w2 * vv.w);
            const float d3 = fmaxf(0.f, w0 * vv.z + w1 * vv.w + w2 * next);
            const int c0 = 4 * l;
            sDT[(c0 + 0) * 66 + n] = f2bf_r(d0);
            sDT[(c0 + 1) * 66 + n] = f2bf_r(d1);
            sDT[(c0 + 2) * 66 + n] = f2bf_r(d2);
            sDT[(c0 + 3) * 66 + n] = f2bf_r(d3);
        }
    }
    __syncthreads();

    bf16x8 pa[2];
#pragma unroll
    for (int kg = 0; kg < 2; ++kg) {
        const unsigned long long* p =
            (const unsigned long long*)&sPw[mt * 16 + lr][kg * 32 + lg * 8];
        U8 u; u.d[0] = p[0]; u.d[1] = p[1];
        pa[kg] = u.v;
    }
    f32x4 acc3[8];
    {
        f32x4 zz = {0.f, 0.f, 0.f, 0.f};
#pragma unroll
        for (int t = 0; t < 8; ++t) acc3[t] = zz;
    }
#pragma unroll
    for (int t = 0; t < 8; ++t) {
        const int ct = h * 8 + t;
#pragma unroll
        for (int kg = 0; kg < 2; ++kg) {
            const unsigned* p = (const unsigned*)&sDT[(ct * 16 + lr) * 66 + kg * 32 + lg * 8];
            U8 u; u.u[0] = p[0]; u.u[1] = p[1]; u.u[2] = p[2]; u.u[3] = p[3];
            acc3[t] = __builtin_amdgcn_mfma_f32_16x16x32_bf16(pa[kg], u.v, acc3[t], 0, 0, 0);
        }
    }
    {
        float s1a[4], s2a[4];
#pragma unroll
        for (int r = 0; r < 4; ++r) {
            float s1 = 0.f, s2 = 0.f;
#pragma unroll
            for (int t = 0; t < 8; ++t) {
                const float x = acc3[t][r];
                s1 += x; s2 += x * x;
            }
#pragma unroll
            for (int off = 1; off < 16; off <<= 1) {
                s1 += __shfl_xor(s1, off);
                s2 += __shfl_xor(s2, off);
            }
            s1a[r] = s1; s2a[r] = s2;
        }
        if (lr == 0) {
#pragma unroll
            for (int r = 0; r < 4; ++r) {
                const int m = mt * 16 + lg * 4 + r;
                sLN[m][2 * h + 0] = s1a[r];
                sLN[m][2 * h + 1] = s2a[r];
            }
        }
    }
    __syncthreads();

    float mus[4], rss[4];
#pragma unroll
    for (int r = 0; r < 4; ++r) {
        const int m = mt * 16 + lg * 4 + r;
        const float S1 = sLN[m][0] + sLN[m][2];
        const float S2 = sLN[m][1] + sLN[m][3];
        const float mu = S1 * (1.f / 256.f);
        const float var = S2 * (1.f / 256.f) - mu * mu;
        mus[r] = mu;
        rss[r] = rsqrtf(var + EPSV);
    }
    {
        float* orow = out + base + (long)(mt * 16 + lg * 4) * NC + lr;
#pragma unroll
        for (int t = 0; t < 8; ++t) {
            const int ct = h * 8 + t;
            const float gg = gam[ct * 16 + lr];
            const float bb = bet[ct * 16 + lr];
#pragma unroll
            for (int r = 0; r < 4; ++r) {
                orow[(long)r * NC + ct * 16] =
                    (acc3[t][r] - mus[r]) * rss[r] * gg + bb;
            }
        }
    }
}

extern "C" void kernel_launch(void* const* d_in, const int* in_sizes, int n_in,
                              void* d_out, int out_size, void* d_ws, size_t ws_size,
                              hipStream_t stream) {
    const float* q   = (const float*)d_in[0];
    const float* v   = (const float*)d_in[1];
    const float* W   = (const float*)d_in[2];
    const float* bl  = (const float*)d_in[3];
    const float* gam = (const float*)d_in[4];
    const float* bet = (const float*)d_in[5];
    float* o = (float*)d_out;

    const size_t WF_SZ  = 40960;                          // W fragments (bf16)
    const size_t CW_OFF = WF_SZ;
    const size_t CW_SZ  = (size_t)NB * 64 * 4 * 4;        // conv weights f32
    const size_t PW_OFF = CW_OFF + CW_SZ;
    const size_t PW_SZ  = (size_t)NB * 64 * 64 * 2;       // point weights bf16
    const size_t NEED   = PW_OFF + PW_SZ;                 // ~18.9 MB

    unsigned short* wf = (unsigned short*)d_ws;
    hipLaunchKernelGGL(prep_wfrag, dim3(10), dim3(256), 0, stream, W, wf);

    if (ws_size >= NEED) {
        float* cw          = (float*)((char*)d_ws + CW_OFF);
        unsigned short* pw = (unsigned short*)((char*)d_ws + PW_OFF);
        hipLaunchKernelGGL(dysep_k1, dim3(NB), dim3(512), 0, stream,
                           q, wf, bl, cw, pw);
        hipLaunchKernelGGL(dysep_k2, dim3(NB), dim3(512), 0, stream,
                           v, cw, pw, gam, bet, o);
    } else {
        hipLaunchKernelGGL(dysep_mfma8, dim3(NB), dim3(512), 0, stream,
                           q, v, wf, bl, gam, bet, o);
    }
}

// Round 9
// 112.407 us; speedup vs baseline: 1.3595x; 1.0641x over previous
//
#include <hip/hip_runtime.h>

#define NB 2048
#define NN 64
#define NC 256
#define EPSV 1e-5f

typedef __attribute__((ext_vector_type(8))) short bf16x8;
typedef __attribute__((ext_vector_type(4))) float f32x4;

union U8 { unsigned u[4]; unsigned long long d[2]; bf16x8 v; };

__device__ __forceinline__ unsigned f_bits(float f) {
    union { float f; unsigned u; } x; x.f = f; return x.u;
}
// round-half-up f32->bf16
__device__ __forceinline__ unsigned short f2bf_r(float f) {
    return (unsigned short)((f_bits(f) + 0x8000u) >> 16);
}
// pack two f32 -> two bf16 in one u32 (lo = a, hi = b)
__device__ __forceinline__ unsigned pack2(float a, float b) {
    return ((f_bits(a) + 0x8000u) >> 16) | ((f_bits(b) + 0x8000u) & 0xffff0000u);
}

// ---- prep: pack W (f32 [67][256]) into bf16 MFMA B-fragments ----
extern "C" __global__ void prep_wfrag(const float* __restrict__ W,
                                      unsigned short* __restrict__ wf)
{
    const int idx = blockIdx.x * 256 + threadIdx.x;  // 0..2559
    if (idx >= 40 * 64) return;
    const int f = idx >> 6, l = idx & 63;
    const int nt = f >> 3, kg = f & 7;
    const int o = nt * 16 + (l & 15);
    const int kb = kg * 32 + (l >> 4) * 8;
    float x[8];
#pragma unroll
    for (int e = 0; e < 8; ++e)
        x[e] = (o < 67) ? W[o * NC + kb + e] : 0.f;
    uint4 pk;
    pk.x = pack2(x[0], x[1]); pk.y = pack2(x[2], x[3]);
    pk.z = pack2(x[4], x[5]); pk.w = pack2(x[6], x[7]);
    *(uint4*)(wf + (size_t)idx * 8) = pk;
}

// Fused kernel, 8 waves, V prefetched into registers at entry.
// __launch_bounds__(512, 4): VGPR cap 128 so vpre(32)+af(32)+acc+staging
// FITS (at (512,6) cap=85 the allocator spilled vpre to scratch: R5/R6).
extern "C" __global__ __launch_bounds__(512, 4)
void dysep_mfma8(const float* __restrict__ q, const float* __restrict__ v,
                 const unsigned short* __restrict__ wfrag,
                 const float* __restrict__ bl,
                 const float* __restrict__ gam, const float* __restrict__ bet,
                 float* __restrict__ out)
{
    // LDS: 33792 + 8704 + 1024 + 1024 = 44544 B
    __shared__ __align__(16) unsigned short sDT[256 * 66];  // depth^T bf16 [c][n], pitch 66
    __shared__ __align__(16) unsigned short sPw[64][68];    // point_w bf16 [m][n], pitch 68
    __shared__ __align__(16) float sCw[64][4];              // conv weights f32
    __shared__ __align__(16) float sLN[64][4];              // LN partials

    const int tid = threadIdx.x;
    const int w  = tid >> 6;        // wave 0..7
    const int mt = w & 3;           // m-tile 0..3
    const int h  = w >> 2;          // half 0/1
    const int l  = tid & 63;
    const int lr = l & 15;
    const int lg = l >> 4;
    const long base = (long)blockIdx.x * (NN * NC);

    // ---- V prefetch FIRST: 8 independent b128 loads, oldest in the vmcnt
    // queue. Phase 1's wait on the (newer) Q/wfrag loads implicitly retires
    // these (in-order vmcnt), so the conv phase pays no extra memory wait:
    // ONE serial HBM exposure per block instead of two. ----
    float4 vpre[8];
#pragma unroll
    for (int i = 0; i < 8; ++i)
        vpre[i] = *(const float4*)(v + base + (long)(i * 8 + w) * NC + 4 * l);

    // ================= Phase 1: dyw = Q @ W^T + b  via MFMA =================
    bf16x8 af[8];
    {
        const float* qrow = q + base + (long)(mt * 16 + lr) * NC + lg * 8;
#pragma unroll
        for (int kg = 0; kg < 8; ++kg) {
            float4 a0 = *(const float4*)(qrow + kg * 32);
            float4 a1 = *(const float4*)(qrow + kg * 32 + 4);
            U8 u;
            u.u[0] = pack2(a0.x, a0.y); u.u[1] = pack2(a0.z, a0.w);
            u.u[2] = pack2(a1.x, a1.y); u.u[3] = pack2(a1.z, a1.w);
            af[kg] = u.v;
        }
    }
    const int ntCount = 3 - h;
    f32x4 acc[3];
    {
        f32x4 zz = {0.f, 0.f, 0.f, 0.f};
#pragma unroll
        for (int t = 0; t < 3; ++t) acc[t] = zz;
    }
    const U8* __restrict__ wf8 = (const U8*)wfrag;
#pragma unroll
    for (int t = 0; t < 3; ++t) {
        if (t < ntCount) {
            const int nt = h * 3 + t;
            const U8* fr = wf8 + (nt * 8) * 64 + l;
#pragma unroll
            for (int kg = 0; kg < 8; ++kg) {
                U8 u = fr[kg * 64];
                acc[t] = __builtin_amdgcn_mfma_f32_16x16x32_bf16(af[kg], u.v, acc[t], 0, 0, 0);
            }
        }
    }
    // epilogue: C/D layout col=lr (o), row=lg*4+r (m)
#pragma unroll
    for (int t = 0; t < 3; ++t) {
        if (t < ntCount) {
            const int o = (h * 3 + t) * 16 + lr;
            const float bb = (o < 67) ? bl[o] : 0.f;
#pragma unroll
            for (int r = 0; r < 4; ++r) {
                const int m = mt * 16 + lg * 4 + r;
                const float val = acc[t][r] + bb;
                if (o < 3) sCw[m][o] = val;
                else if (o < 67) sPw[m][o - 3] = f2bf_r(val);
            }
        }
    }
    __syncthreads();

    // ====== Phase 2: depth^T[c][n] = relu(conv3(vpre, cw[n])) (bf16) ======
    {
#pragma unroll
        for (int i = 0; i < 8; ++i) {       // FULL unroll: vpre[i] static index
            const int n = i * 8 + w;
            const float w0 = sCw[n][0], w1 = sCw[n][1], w2 = sCw[n][2];
            float4 vv = vpre[i];
            float prev = __shfl(vv.w, (l + 63) & 63);
            float next = __shfl(vv.x, (l + 1) & 63);
            if (l == 0) prev = 0.f;
            if (l == 63) next = 0.f;
            const float d0 = fmaxf(0.f, w0 * prev + w1 * vv.x + w2 * vv.y);
            const float d1 = fmaxf(0.f, w0 * vv.x + w1 * vv.y + w2 * vv.z);
            const float d2 = fmaxf(0.f, w0 * vv.y + w1 * vv.z + w2 * vv.w);
            const float d3 = fmaxf(0.f, w0 * vv.z + w1 * vv.w + w2 * next);
            const int c0 = 4 * l;
            sDT[(c0 + 0) * 66 + n] = f2bf_r(d0);
            sDT[(c0 + 1) * 66 + n] = f2bf_r(d1);
            sDT[(c0 + 2) * 66 + n] = f2bf_r(d2);
            sDT[(c0 + 3) * 66 + n] = f2bf_r(d3);
        }
    }
    __syncthreads();

    // ======== Phase 3: point = pw @ depth via MFMA (wave: mt x c-half h) ========
    bf16x8 pa[2];
#pragma unroll
    for (int kg = 0; kg < 2; ++kg) {
        const unsigned long long* p =
            (const unsigned long long*)&sPw[mt * 16 + lr][kg * 32 + lg * 8];
        U8 u; u.d[0] = p[0]; u.d[1] = p[1];
        pa[kg] = u.v;
    }
    f32x4 acc3[8];
    {
        f32x4 zz = {0.f, 0.f, 0.f, 0.f};
#pragma unroll
        for (int t = 0; t < 8; ++t) acc3[t] = zz;
    }
#pragma unroll
    for (int t = 0; t < 8; ++t) {
        const int ct = h * 8 + t;
#pragma unroll
        for (int kg = 0; kg < 2; ++kg) {
            const unsigned* p = (const unsigned*)&sDT[(ct * 16 + lr) * 66 + kg * 32 + lg * 8];
            U8 u; u.u[0] = p[0]; u.u[1] = p[1]; u.u[2] = p[2]; u.u[3] = p[3];
            acc3[t] = __builtin_amdgcn_mfma_f32_16x16x32_bf16(pa[kg], u.v, acc3[t], 0, 0, 0);
        }
    }
    // partial LN sums over this wave's 8 c-tiles; butterfly over lr (within 16)
    {
        float s1a[4], s2a[4];
#pragma unroll
        for (int r = 0; r < 4; ++r) {
            float s1 = 0.f, s2 = 0.f;
#pragma unroll
            for (int t = 0; t < 8; ++t) {
                const float x = acc3[t][r];
                s1 += x; s2 += x * x;
            }
#pragma unroll
            for (int off = 1; off < 16; off <<= 1) {
                s1 += __shfl_xor(s1, off);
                s2 += __shfl_xor(s2, off);
            }
            s1a[r] = s1; s2a[r] = s2;
        }
        if (lr == 0) {
#pragma unroll
            for (int r = 0; r < 4; ++r) {
                const int m = mt * 16 + lg * 4 + r;
                sLN[m][2 * h + 0] = s1a[r];
                sLN[m][2 * h + 1] = s2a[r];
            }
        }
    }
    __syncthreads();

    float mus[4], rss[4];
#pragma unroll
    for (int r = 0; r < 4; ++r) {
        const int m = mt * 16 + lg * 4 + r;
        const float S1 = sLN[m][0] + sLN[m][2];
        const float S2 = sLN[m][1] + sLN[m][3];
        const float mu = S1 * (1.f / 256.f);
        const float var = S2 * (1.f / 256.f) - mu * mu;
        mus[r] = mu;
        rss[r] = rsqrtf(var + EPSV);
    }
    {
        float* orow = out + base + (long)(mt * 16 + lg * 4) * NC + lr;
#pragma unroll
        for (int t = 0; t < 8; ++t) {
            const int ct = h * 8 + t;
            const float gg = gam[ct * 16 + lr];
            const float bb = bet[ct * 16 + lr];
#pragma unroll
            for (int r = 0; r < 4; ++r) {
                orow[(long)r * NC + ct * 16] =
                    (acc3[t][r] - mus[r]) * rss[r] * gg + bb;
            }
        }
    }
}

extern "C" void kernel_launch(void* const* d_in, const int* in_sizes, int n_in,
                              void* d_out, int out_size, void* d_ws, size_t ws_size,
                              hipStream_t stream) {
    const float* q   = (const float*)d_in[0];
    const float* v   = (const float*)d_in[1];
    const float* W   = (const float*)d_in[2];
    const float* bl  = (const float*)d_in[3];
    const float* gam = (const float*)d_in[4];
    const float* bet = (const float*)d_in[5];
    float* o = (float*)d_out;
    unsigned short* wf = (unsigned short*)d_ws;   // 40*64*16 B = 40960 B

    hipLaunchKernelGGL(prep_wfrag, dim3(10), dim3(256), 0, stream, W, wf);
    hipLaunchKernelGGL(dysep_mfma8, dim3(NB), dim3(512), 0, stream,
                       q, v, wf, bl, gam, bet, o);
}